// Round 7
// baseline (157.213 us; speedup 1.0000x reference)
//
#include <hip/hip_runtime.h>

constexpr int Bn = 32;
constexpr int Cn = 256;
constexpr int Nn = 1024;

constexpr float C2 = 2.8853900817779268f;  // 2/ln2
constexpr float K1 = 1.4426950408889634f;  // 1/ln2

typedef __bf16 v8bf  __attribute__((ext_vector_type(8)));
typedef float  v16f  __attribute__((ext_vector_type(16)));

// hbf layout (byte-identical to previous rounds): [b][nt32][c][32n] bf16.
// nt32 block = 16384 B, c-row = 64 B holding n = nt32*32 + [0,32) as four
// 16-B groups; group g (= (n>>3)&3) stored at position (g ^ (c&3));
// within group: byte (n&7)*2.

// ---------------------------------------------------------------------------
// FUSED persistent kernel with per-b flag handshake (no cooperative launch,
// no grid sync). Phase A = round-4 prep (register-direct, no LDS transpose).
// Then: release-atomicAdd(flag[b]); spin until flag[b]==16; acquire.
// Phase B = round-4 ctx (double-buffered est, 1 barrier/tile), unchanged.
// Grid 512 = exactly 2 blocks/CU x 256 CU co-resident (LDS 68096x2 <= 160K,
// VGPR <= 128 via launch_bounds(512,4)) -> spin is deadlock-free; bounded
// spin (fails visibly, never hangs) as a safety net.
// Agent-scope release/acquire gives cross-XCD visibility regardless of the
// (undefined) block->XCD mapping.
// ---------------------------------------------------------------------------
constexpr int EST_OFF  = 0;               // est[2][64][128B] = 16384
constexpr int QS_OFF   = 16384;           // qs 4096; comb[64][257] aliases [0,65792)
constexpr int SP_OFF   = 65792;
constexpr int SINV_OFF = 67840;
constexpr int CTX_SMEM = 68096;
// phase-A overlay (dead before phase B writes est):
constexpr int P1_OFF   = 0;               // p1[8][64] f32 = 2048
constexpr int P2_OFF   = 2048;            // p2[8][64] f32 = 2048

__global__ __launch_bounds__(512, 4) void fused_kernel(
    const float* __restrict__ h,
    const float* __restrict__ w1, const float* __restrict__ w1b,
    const float* __restrict__ w2, const float* __restrict__ w2b,
    float* __restrict__ pa_g, float* __restrict__ q_g,
    unsigned char* __restrict__ hbf,
    float* __restrict__ out,
    unsigned int* __restrict__ flags)
{
    __shared__ alignas(16) unsigned char smem[CTX_SMEM];

    int blk = blockIdx.x;
    int xcd = blk & 7, idx = blk >> 3;
    int b   = xcd * 4 + (idx >> 4);
    int n0  = (idx & 15) * 64;           // phase A: n-slice; phase B: i-slice
    int t = threadIdx.x, w = t >> 6, l = t & 63;

    // ======================= phase A: prep =======================
    {
        float (*p1)[64] = (float(*)[64])(smem + P1_OFF);
        float (*p2)[64] = (float(*)[64])(smem + P2_OFF);
        int co = l >> 3, oct = l & 7;

        float s1[8], s2[8];
#pragma unroll
        for (int j = 0; j < 8; ++j) { s1[j] = 0.f; s2[j] = 0.f; }

        const float* hb = h + (size_t)b * Cn * Nn + n0 + oct * 8;
        int nt32 = (n0 >> 5) + (oct >> 2);
        unsigned char* nt_base = hbf + (size_t)(b * 32 + nt32) * 16384;
        int g = oct & 3;

#pragma unroll
        for (int it = 0; it < 4; ++it) {
            int c = it * 64 + w * 8 + co;
            const float* src = hb + (size_t)c * Nn;
            float4 va = *(const float4*)src;
            float4 vb = *(const float4*)(src + 4);
            float w1c = w1[c], w2c = w2[c];
            float v[8] = {va.x, va.y, va.z, va.w, vb.x, vb.y, vb.z, vb.w};
            union { __bf16 bx[8]; uint4 u4; } pk;
#pragma unroll
            for (int j = 0; j < 8; ++j) {
                s1[j] = fmaf(v[j], w1c, s1[j]);
                s2[j] = fmaf(v[j], w2c, s2[j]);
                pk.bx[j] = (__bf16)v[j];
            }
            *(uint4*)(nt_base + c * 64 + ((g ^ (c & 3)) << 4)) = pk.u4;
        }

        // reduce the 8 c-offset lanes sharing this n-octet
#pragma unroll
        for (int m = 8; m <= 32; m <<= 1) {
#pragma unroll
            for (int j = 0; j < 8; ++j) {
                s1[j] += __shfl_xor(s1[j], m);
                s2[j] += __shfl_xor(s2[j], m);
            }
        }
        if (co == 0) {
#pragma unroll
            for (int j = 0; j < 8; ++j) {
                p1[w][oct * 8 + j] = s1[j];
                p2[w][oct * 8 + j] = s2[j];
            }
        }
        __syncthreads();                 // hbf stores drained (vmcnt0/wave)
        if (t < 64) {
            float a = w1b[0], k = w2b[0];
#pragma unroll
            for (int ww = 0; ww < 8; ++ww) { a += p1[ww][t]; k += p2[ww][t]; }
            pa_g[b * Nn + n0 + t] = exp2f(C2 * a);
            q_g [b * Nn + n0 + t] = exp2f(C2 * k);
        }
    }

    // =============== per-b handshake (release / spin / acquire) ===============
    if (t == 0) {
        // release: drains wave-0's pa/q stores (vmcnt) + writes back L2;
        // hbf stores by all waves already drained to L2 at the barrier above.
        __hip_atomic_fetch_add(flags + b, 1u, __ATOMIC_RELEASE,
                               __HIP_MEMORY_SCOPE_AGENT);
        int guard = 0;
        while (__hip_atomic_load(flags + b, __ATOMIC_RELAXED,
                                 __HIP_MEMORY_SCOPE_AGENT) < 16u &&
               guard < (1 << 22)) {
            __builtin_amdgcn_s_sleep(8);
            ++guard;
        }
        (void)__hip_atomic_load(flags + b, __ATOMIC_ACQUIRE,
                                __HIP_MEMORY_SCOPE_AGENT);
    }
    __syncthreads();                     // all waves held until b is complete

    // ======================= phase B: ctx =======================
    float* qs           = (float*)(smem + QS_OFF);
    float (*Sp)[64]     = (float(*)[64])(smem + SP_OFF);
    float* Sinv         = (float*)(smem + SINV_OFF);
    float (*comb)[257]  = (float(*)[257])smem;

    int i0 = n0;
    int lm = l & 31, lh = l >> 5;
    int cq = w & 3, wq = w >> 2;

    const unsigned char* hbf_b = hbf + (size_t)b * 524288;

    for (int i = t; i < Nn; i += 512) qs[i] = q_g[b * Nn + i];
    float pav = pa_g[b * Nn + i0 + l];          // gen row = l

    v16f acc[2][2];
#pragma unroll
    for (int x = 0; x < 2; ++x)
#pragma unroll
        for (int y = 0; y < 2; ++y)
#pragma unroll
            for (int r = 0; r < 16; ++r) acc[x][y][r] = 0.f;
    float Spart = 0.f;

    int est_sw = l * 128 + ((w ^ (l & 7)) << 4);

    // loop-invariant B-frag byte offsets within an nt32 block:
    int cB   = cq * 64 + lm;
    int m4   = cB & 3;
    int off0 = cB * 64 + ((lh ^ m4) << 4);          // ks = 0
    int off1 = cB * 64 + (((2 + lh) ^ m4) << 4);    // ks = 1

    __syncthreads();                     // qs published
    for (int tt = 0; tt < 16; ++tt) {
        unsigned char* est_base = smem + EST_OFF + ((tt & 1) << 13);
        // ---- B-frags for this tile: 4 x 16B global loads (L2-hot) ----
        const unsigned char* pt = hbf_b + (size_t)((wq << 4) + tt) * 16384;
        v8bf b00 = *(const v8bf*)(pt + off0);
        v8bf b01 = *(const v8bf*)(pt + off0 + 2048);
        v8bf b10 = *(const v8bf*)(pt + off1);
        v8bf b11 = *(const v8bf*)(pt + off1 + 2048);
        // ---- generate E into buffer tt&1 ----
        {
            int qb = wq * 512 + tt * 32 + cq * 8;
            float4 q0 = *(const float4*)&qs[qb];
            float4 q1 = *(const float4*)&qs[qb + 4];
            float qv[8] = {q0.x, q0.y, q0.z, q0.w, q1.x, q1.y, q1.z, q1.w};
            v8bf ev;
#pragma unroll
            for (int j = 0; j < 8; ++j) {
                float z = pav * qv[j];                       // e^{2(a+k)}
                float r = __builtin_amdgcn_rcpf(1.f + z);
                float e = exp2f(fmaf(r, -2.f * K1, K1));     // e^{tanh}
                __bf16 eb = (__bf16)e;
                ev[j] = eb;
                Spart += (float)eb;
            }
            *(v8bf*)(est_base + est_sw) = ev;
        }
        __syncthreads();                 // est[tt&1] published; tt-1 reads drained
        // ---- MFMA phase: 4 A ds_reads + 8 MFMA ----
#pragma unroll
        for (int ks = 0; ks < 2; ++ks) {
            int gA = ((wq << 2) + (ks << 1) + lh) ^ (lm & 7);
            v8bf a0 = *(const v8bf*)(est_base + lm * 128        + (gA << 4));
            v8bf a1 = *(const v8bf*)(est_base + (32 + lm) * 128 + (gA << 4));
            v8bf b0 = ks ? b10 : b00;
            v8bf b1 = ks ? b11 : b01;
            acc[0][0] = __builtin_amdgcn_mfma_f32_32x32x16_bf16(a0, b0, acc[0][0], 0, 0, 0);
            acc[0][1] = __builtin_amdgcn_mfma_f32_32x32x16_bf16(a0, b1, acc[0][1], 0, 0, 0);
            acc[1][0] = __builtin_amdgcn_mfma_f32_32x32x16_bf16(a1, b0, acc[1][0], 0, 0, 0);
            acc[1][1] = __builtin_amdgcn_mfma_f32_32x32x16_bf16(a1, b1, acc[1][1], 0, 0, 0);
        }
    }

    // ---- epilogue (identical) ----
    Sp[w][l] = Spart;
    __syncthreads();                     // est/qs dead -> comb alias safe
    if (t < 64) {
        float S = 0.f;
#pragma unroll
        for (int ww = 0; ww < 8; ++ww) S += Sp[ww][t];
        Sinv[t] = 1.f / S;
    }
    if (wq == 1) {
#pragma unroll
        for (int x = 0; x < 2; ++x)
#pragma unroll
            for (int y = 0; y < 2; ++y)
#pragma unroll
                for (int r = 0; r < 16; ++r) {
                    int rl = (r & 3) + 8 * (r >> 2) + 4 * lh;
                    comb[x * 32 + rl][cq * 64 + y * 32 + lm] = acc[x][y][r];
                }
    }
    __syncthreads();
    if (wq == 0) {
#pragma unroll
        for (int x = 0; x < 2; ++x)
#pragma unroll
            for (int y = 0; y < 2; ++y)
#pragma unroll
                for (int r = 0; r < 16; ++r) {
                    int rl  = (r & 3) + 8 * (r >> 2) + 4 * lh;
                    int row = x * 32 + rl;
                    int col = cq * 64 + y * 32 + lm;
                    float v = (acc[x][y][r] + comb[row][col]) * Sinv[row];
                    v = (v >= 0.f) ? v : 0.2f * v;
                    comb[row][col] = v;
                }
    }
    __syncthreads();
    float* ob = out + (size_t)b * Cn * Nn + i0;
#pragma unroll
    for (int p = 0; p < 8; ++p) {
        int slot = t + (p << 9);
        int c    = slot >> 4;
        int i4   = (slot & 15) << 2;
        float4 o;
        o.x = comb[i4 + 0][c];
        o.y = comb[i4 + 1][c];
        o.z = comb[i4 + 2][c];
        o.w = comb[i4 + 3][c];
        *(float4*)(ob + (size_t)c * Nn + i4) = o;
    }
}

// ---------------------------------------------------------------------------
extern "C" void kernel_launch(void* const* d_in, const int* in_sizes, int n_in,
                              void* d_out, int out_size, void* d_ws, size_t ws_size,
                              hipStream_t stream) {
    const float* h   = (const float*)d_in[0];
    const float* w1w = (const float*)d_in[1];
    const float* w1b = (const float*)d_in[2];
    const float* w2w = (const float*)d_in[3];
    const float* w2b = (const float*)d_in[4];
    float* out = (float*)d_out;

    float* pa_ws = (float*)d_ws;                              // [0, 128K)
    float* q_ws  = pa_ws + Bn * Nn;                           // [128K, 256K)
    unsigned char* hbf = (unsigned char*)d_ws + 262144;       // 16 MB blocked bf16
    unsigned int* flags = (unsigned int*)((unsigned char*)d_ws + 17039360);

    hipMemsetAsync(flags, 0, Bn * sizeof(unsigned int), stream);
    fused_kernel<<<512, 512, 0, stream>>>(h, w1w, w1b, w2w, w2b,
                                          pa_ws, q_ws, hbf, out, flags);
}

// Round 10
// 120.013 us; speedup vs baseline: 1.3100x; 1.3100x over previous
//
#include <hip/hip_runtime.h>

constexpr int Bn = 32;
constexpr int Cn = 256;
constexpr int Nn = 1024;

constexpr float C2 = 2.8853900817779268f;  // 2/ln2
constexpr float K1 = 1.4426950408889634f;  // 1/ln2

typedef __bf16 v8bf  __attribute__((ext_vector_type(8)));
typedef float  v16f  __attribute__((ext_vector_type(16)));
typedef float  v4f   __attribute__((ext_vector_type(4)));   // clang vector: ok for nontemporal builtins

// hbf layout (byte-identical to previous rounds): [b][nt32][c][32n] bf16.
// nt32 block = 16384 B, c-row = 64 B holding n = nt32*32 + [0,32) as four
// 16-B groups; group g (= (n>>3)&3) stored at position (g ^ (c&3));
// within group: byte (n&7)*2.

// ---------------------------------------------------------------------------
// Prep (round-4 register-direct version + nontemporal h loads): lane L =
// (c-offset L>>3, n-octet L&7) loads h directly (2 x v4f nt), converts to
// bf16 in-register, stores its 16-B granule straight to hbf at the XOR slot.
// Dot products via 3 __shfl_xor steps + 4 KB LDS cross-wave combine.
// nt on h: streamed exactly once per iteration -> evict-first, less L2/L3
// pollution for hbf/out.
// ---------------------------------------------------------------------------
__global__ __launch_bounds__(512) void prep_kernel(
    const float* __restrict__ h,
    const float* __restrict__ w1, const float* __restrict__ w1b,
    const float* __restrict__ w2, const float* __restrict__ w2b,
    float* __restrict__ pa_g, float* __restrict__ q_g,
    unsigned char* __restrict__ hbf)
{
    int blk = blockIdx.x;
    int xcd = blk & 7, idx = blk >> 3;
    int b   = xcd * 4 + (idx >> 4);
    int n0  = (idx & 15) * 64;
    int t = threadIdx.x, w = t >> 6, l = t & 63;
    int co = l >> 3, oct = l & 7;

    __shared__ float p1[8][64], p2[8][64];

    float s1[8], s2[8];
#pragma unroll
    for (int j = 0; j < 8; ++j) { s1[j] = 0.f; s2[j] = 0.f; }

    const float* hb = h + (size_t)b * Cn * Nn + n0 + oct * 8;
    int nt32 = (n0 >> 5) + (oct >> 2);
    unsigned char* nt_base = hbf + (size_t)(b * 32 + nt32) * 16384;
    int g = oct & 3;

#pragma unroll
    for (int it = 0; it < 4; ++it) {
        int c = it * 64 + w * 8 + co;
        const float* src = hb + (size_t)c * Nn;
        v4f va = __builtin_nontemporal_load((const v4f*)src);
        v4f vb = __builtin_nontemporal_load((const v4f*)(src + 4));
        float w1c = w1[c], w2c = w2[c];
        float v[8] = {va.x, va.y, va.z, va.w, vb.x, vb.y, vb.z, vb.w};
        union { __bf16 bx[8]; uint4 u4; } pk;
#pragma unroll
        for (int j = 0; j < 8; ++j) {
            s1[j] = fmaf(v[j], w1c, s1[j]);
            s2[j] = fmaf(v[j], w2c, s2[j]);
            pk.bx[j] = (__bf16)v[j];
        }
        *(uint4*)(nt_base + c * 64 + ((g ^ (c & 3)) << 4)) = pk.u4;
    }

    // reduce the 8 c-offset lanes sharing this n-octet (lanes l ^ {8,16,32})
#pragma unroll
    for (int m = 8; m <= 32; m <<= 1) {
#pragma unroll
        for (int j = 0; j < 8; ++j) {
            s1[j] += __shfl_xor(s1[j], m);
            s2[j] += __shfl_xor(s2[j], m);
        }
    }
    if (co == 0) {
#pragma unroll
        for (int j = 0; j < 8; ++j) {
            p1[w][oct * 8 + j] = s1[j];
            p2[w][oct * 8 + j] = s2[j];
        }
    }
    __syncthreads();
    if (t < 64) {
        float a = w1b[0], k = w2b[0];
#pragma unroll
        for (int ww = 0; ww < 8; ++ww) { a += p1[ww][t]; k += p2[ww][t]; }
        pa_g[b * Nn + n0 + t] = exp2f(C2 * a);
        q_g [b * Nn + n0 + t] = exp2f(C2 * k);
    }
}

// ---------------------------------------------------------------------------
// Ctx: round-1/4 known-good kernel (double-buffered est, one barrier per
// tile) + nontemporal out stores (out is written once, never re-read).
// ---------------------------------------------------------------------------
constexpr int EST_OFF  = 0;               // est[2][64][128B] = 16384
constexpr int QS_OFF   = 16384;           // qs 4096; comb[64][257] aliases [0,65792)
constexpr int SP_OFF   = 65792;
constexpr int SINV_OFF = 67840;
constexpr int CTX_SMEM = 68096;

__global__ __launch_bounds__(512, 4) void ctx_kernel(
    const unsigned char* __restrict__ hbf,
    const float* __restrict__ pa_g, const float* __restrict__ q_g,
    float* __restrict__ out)
{
    __shared__ alignas(16) unsigned char smem[CTX_SMEM];
    float* qs           = (float*)(smem + QS_OFF);
    float (*Sp)[64]     = (float(*)[64])(smem + SP_OFF);
    float* Sinv         = (float*)(smem + SINV_OFF);
    float (*comb)[257]  = (float(*)[257])smem;

    int blk = blockIdx.x;
    int xcd = blk & 7, slot = blk >> 3;
    int b   = xcd * 4 + (slot >> 4);
    int i0  = (slot & 15) * 64;

    int t = threadIdx.x, w = t >> 6, l = t & 63;
    int lm = l & 31, lh = l >> 5;
    int cq = w & 3, wq = w >> 2;

    const unsigned char* hbf_b = hbf + (size_t)b * 524288;

    for (int i = t; i < Nn; i += 512) qs[i] = q_g[b * Nn + i];
    float pav = pa_g[b * Nn + i0 + l];          // gen row = l

    v16f acc[2][2];
#pragma unroll
    for (int x = 0; x < 2; ++x)
#pragma unroll
        for (int y = 0; y < 2; ++y)
#pragma unroll
            for (int r = 0; r < 16; ++r) acc[x][y][r] = 0.f;
    float Spart = 0.f;

    int est_sw = l * 128 + ((w ^ (l & 7)) << 4);

    // loop-invariant B-frag byte offsets within an nt32 block:
    // c = cq*64 + lm (s=1 adds +2048 = 32 c-rows); group g = ks*2 + lh at
    // physical position (g ^ (c&3)).
    int cB   = cq * 64 + lm;
    int m4   = cB & 3;
    int off0 = cB * 64 + ((lh ^ m4) << 4);          // ks = 0
    int off1 = cB * 64 + (((2 + lh) ^ m4) << 4);    // ks = 1

    __syncthreads();                     // qs published
    for (int tt = 0; tt < 16; ++tt) {
        unsigned char* est_base = smem + EST_OFF + ((tt & 1) << 13);
        // ---- B-frags for this tile: 4 x 16B global loads (L2-hot),
        //      issued before gen so they land under gen + barrier ----
        const unsigned char* pt = hbf_b + (size_t)((wq << 4) + tt) * 16384;
        v8bf b00 = *(const v8bf*)(pt + off0);
        v8bf b01 = *(const v8bf*)(pt + off0 + 2048);
        v8bf b10 = *(const v8bf*)(pt + off1);
        v8bf b11 = *(const v8bf*)(pt + off1 + 2048);
        // ---- generate E into buffer tt&1 ----
        {
            int qb = wq * 512 + tt * 32 + cq * 8;
            float4 q0 = *(const float4*)&qs[qb];
            float4 q1 = *(const float4*)&qs[qb + 4];
            float qv[8] = {q0.x, q0.y, q0.z, q0.w, q1.x, q1.y, q1.z, q1.w};
            v8bf ev;
#pragma unroll
            for (int j = 0; j < 8; ++j) {
                float z = pav * qv[j];                       // e^{2(a+k)}
                float r = __builtin_amdgcn_rcpf(1.f + z);
                float e = exp2f(fmaf(r, -2.f * K1, K1));     // e^{tanh}
                __bf16 eb = (__bf16)e;
                ev[j] = eb;
                Spart += (float)eb;
            }
            *(v8bf*)(est_base + est_sw) = ev;
        }
        __syncthreads();                 // est[tt&1] published; tt-1 reads drained
        // ---- MFMA phase: 4 A ds_reads + 8 MFMA ----
#pragma unroll
        for (int ks = 0; ks < 2; ++ks) {
            int gA = ((wq << 2) + (ks << 1) + lh) ^ (lm & 7);
            v8bf a0 = *(const v8bf*)(est_base + lm * 128        + (gA << 4));
            v8bf a1 = *(const v8bf*)(est_base + (32 + lm) * 128 + (gA << 4));
            v8bf b0 = ks ? b10 : b00;
            v8bf b1 = ks ? b11 : b01;
            acc[0][0] = __builtin_amdgcn_mfma_f32_32x32x16_bf16(a0, b0, acc[0][0], 0, 0, 0);
            acc[0][1] = __builtin_amdgcn_mfma_f32_32x32x16_bf16(a0, b1, acc[0][1], 0, 0, 0);
            acc[1][0] = __builtin_amdgcn_mfma_f32_32x32x16_bf16(a1, b0, acc[1][0], 0, 0, 0);
            acc[1][1] = __builtin_amdgcn_mfma_f32_32x32x16_bf16(a1, b1, acc[1][1], 0, 0, 0);
        }
    }

    // ---- epilogue (identical) ----
    Sp[w][l] = Spart;
    __syncthreads();                     // est/qs dead -> comb alias safe
    if (t < 64) {
        float S = 0.f;
#pragma unroll
        for (int ww = 0; ww < 8; ++ww) S += Sp[ww][t];
        Sinv[t] = 1.f / S;
    }
    if (wq == 1) {
#pragma unroll
        for (int x = 0; x < 2; ++x)
#pragma unroll
            for (int y = 0; y < 2; ++y)
#pragma unroll
                for (int r = 0; r < 16; ++r) {
                    int rl = (r & 3) + 8 * (r >> 2) + 4 * lh;
                    comb[x * 32 + rl][cq * 64 + y * 32 + lm] = acc[x][y][r];
                }
    }
    __syncthreads();
    if (wq == 0) {
#pragma unroll
        for (int x = 0; x < 2; ++x)
#pragma unroll
            for (int y = 0; y < 2; ++y)
#pragma unroll
                for (int r = 0; r < 16; ++r) {
                    int rl  = (r & 3) + 8 * (r >> 2) + 4 * lh;
                    int row = x * 32 + rl;
                    int col = cq * 64 + y * 32 + lm;
                    float v = (acc[x][y][r] + comb[row][col]) * Sinv[row];
                    v = (v >= 0.f) ? v : 0.2f * v;
                    comb[row][col] = v;
                }
    }
    __syncthreads();
    float* ob = out + (size_t)b * Cn * Nn + i0;
#pragma unroll
    for (int p = 0; p < 8; ++p) {
        int slot = t + (p << 9);
        int c    = slot >> 4;
        int i4   = (slot & 15) << 2;
        v4f o;
        o.x = comb[i4 + 0][c];
        o.y = comb[i4 + 1][c];
        o.z = comb[i4 + 2][c];
        o.w = comb[i4 + 3][c];
        __builtin_nontemporal_store(o, (v4f*)(ob + (size_t)c * Nn + i4));
    }
}

// ---------------------------------------------------------------------------
extern "C" void kernel_launch(void* const* d_in, const int* in_sizes, int n_in,
                              void* d_out, int out_size, void* d_ws, size_t ws_size,
                              hipStream_t stream) {
    const float* h   = (const float*)d_in[0];
    const float* w1w = (const float*)d_in[1];
    const float* w1b = (const float*)d_in[2];
    const float* w2w = (const float*)d_in[3];
    const float* w2b = (const float*)d_in[4];
    float* out = (float*)d_out;

    float* pa_ws = (float*)d_ws;                              // [0, 128K)
    float* q_ws  = pa_ws + Bn * Nn;                           // [128K, 256K)
    unsigned char* hbf = (unsigned char*)d_ws + 262144;       // 16 MB blocked bf16

    prep_kernel<<<512, 512, 0, stream>>>(h, w1w, w1b, w2w, w2b, pa_ws, q_ws, hbf);
    ctx_kernel <<<512, 512, 0, stream>>>(hbf, pa_ws, q_ws, out);
}